// Round 14
// baseline (393.551 us; speedup 1.0000x reference)
//
#include <hip/hip_runtime.h>

#define HH 1024
#define WW 1024
#define NIMG 12

// Same-wave LDS write->read ordering fence. DS ops may complete out of order
// (LGKM counter semantics), and hipcc can hoist ops past inline-asm waitcnt
// (guide rule #18), so: hard waitcnt + scheduler barrier.
#define LDS_FENCE() do { \
    asm volatile("s_waitcnt lgkmcnt(0)" ::: "memory"); \
    __builtin_amdgcn_sched_barrier(0); \
  } while (0)

struct RowLd { float v0, v1, wc; };

// Loads for row ry: center (all lanes) + predicated halo lanes.
// lanes 0..6 load x[col-7], lanes 57..63 load x[col+7].
__device__ __forceinline__ RowLd row_load(const float* __restrict__ s, int ry, int col, int lane) {
  RowLd t;
  if ((unsigned)ry < (unsigned)HH) {
    const float* r = s + (size_t)ry * WW;
    t.v0 = (lane < 7 && col >= 7)        ? r[col - 7] : 0.0f;
    t.v1 = (lane >= 57 && col + 7 < WW)  ? r[col + 7] : 0.0f;
    t.wc = r[col];
  } else { t.v0 = 0.0f; t.v1 = 0.0f; t.wc = 0.0f; }
  return t;
}

// Stage one row into this wave's 80-float LDS strip: st[7+l] = x[c0+l],
// halos at st[0..6] (lanes 0..6) and st[71..77] (lanes 57..63).
__device__ __forceinline__ void stage_row(float* st, const RowLd& t, int lane) {
  st[7 + lane] = t.wc;
  if (lane < 7 || lane >= 57) {
    const int   ha = (lane < 7) ? lane : (lane + 14);
    const float hv = (lane < 7) ? t.v0 : t.v1;
    st[ha] = hv;
  }
}

// lh = sum x[c-7..c], rh = sum x[c..c+7], with EXACTLY the fwd8/bwd8 balanced
// tree grouping -> bitwise-identical to the shuffle implementation.
__device__ __forceinline__ void tree_sums(const float* st, int lane, float wc,
                                          float& lh, float& rh) {
  const float* p = st + 7 + lane;
  float a0 = p[-7], a1 = p[-6], a2 = p[-5], a3 = p[-4], a4 = p[-3], a5 = p[-2], a6 = p[-1];
  float b1 = p[1],  b2 = p[2],  b3 = p[3],  b4 = p[4],  b5 = p[5],  b6 = p[6],  b7 = p[7];
  lh = ((a0 + a1) + (a2 + a3)) + ((a4 + a5) + (a6 + wc));
  rh = ((wc + b1) + (b2 + b3)) + ((b4 + b5) + (b6 + b7));
}

// first-wins argmin combine: keep a unless |b| strictly smaller (tie -> a).
__device__ __forceinline__ float winner(float a, float b) {
  return (fabsf(b) < fabsf(a)) ? b : a;
}

__device__ __forceinline__ float out_px(float ua, float ub, float uc,
                                        float da, float db, float dc,
                                        float lh0, float rh0, float w0) {
  const float ih = 1.0f / 120.0f, iq = 1.0f / 64.0f;
  const float nw0 = -w0;
  const float Ls = ua + da - lh0;
  const float Rs = ub + db - rh0;
  const float Us = ua + ub - uc;
  const float Ds = da + db - dc;
  float d0 = fmaf(Ls, ih, nw0);
  float d1 = fmaf(Rs, ih, nw0);
  float d2 = fmaf(Us, ih, nw0);
  float d3 = fmaf(Ds, ih, nw0);
  float d4 = fmaf(ua, iq, nw0);
  float d5 = fmaf(ub, iq, nw0);
  float d6 = fmaf(da, iq, nw0);
  float d7 = fmaf(db, iq, nw0);
  float w01 = winner(d0, d1), w23 = winner(d2, d3);
  float w45 = winner(d4, d5), w67 = winner(d6, d7);
  float bd = winner(winner(w01, w23), winner(w45, w67));
  return w0 + bd;
}

// One SWF step. Wave owns a 64-col x 32-row tile; 16-deep register ring of
// (lh, rh, w); sliding vertical windows; TWO rows per iteration. Horizontal
// windows via LDS row-staging (1 DS latency level) with explicit lgkmcnt
// fences for same-wave cross-lane visibility.
__global__ __launch_bounds__(256, 4) void swf_step(const float* __restrict__ src,
                                                   float* __restrict__ dst) {
  const int lane = threadIdx.x & 63;
  const int wid  = threadIdx.x >> 6;
  const int col  = blockIdx.x * 64 + lane;
  const int y0   = (blockIdx.y * 4 + wid) * 32;
  const float* s = src + (size_t)blockIdx.z * HH * WW;
  float* d       = dst + (size_t)blockIdx.z * HH * WW;

  __shared__ float smem[4][2][80];   // per-wave double row strip

  float rlh[16], rrh[16], rw[16];

  // Prologue: rows y0-8 .. y0+6 into slot row&15 = (j+8)&15.
  #pragma unroll
  for (int j = 0; j < 15; ++j) {
    const int slot = (j + 8) & 15;
    RowLd t = row_load(s, y0 - 8 + j, col, lane);
    float* st = smem[wid][j & 1];
    LDS_FENCE();                      // WAR: prior reads of this buffer done
    stage_row(st, t, lane);
    LDS_FENCE();                      // RAW: writes visible before reads
    tree_sums(st, lane, t.wc, rlh[slot], rrh[slot]);
    rw[slot] = t.wc;
  }

  // Sliding accumulators for "previous output row" y0-1.
  float ua = 0.f, ub = 0.f, uc = 0.f, da = 0.f, db = 0.f, dc = 0.f;
  #pragma unroll
  for (int j = 0; j < 8; ++j) {
    const int sl = (8 + j) & 15;
    ua += rlh[sl]; ub += rrh[sl]; uc += rw[sl];
  }
  #pragma unroll
  for (int j = 0; j < 8; ++j) {
    const int sl = (15 + j) & 15;
    da += rlh[sl]; db += rrh[sl]; dc += rw[sl];
  }

  // Load pipe: slot(row) = (row - y0 - 7) & 7. Prime rows y0+7..y0+10.
  RowLd pipe[8];
  #pragma unroll
  for (int k = 0; k < 4; ++k) pipe[k] = row_load(s, y0 + 7 + k, col, lane);

  #pragma unroll 1
  for (int yb = 0; yb < 32; yb += 16) {
    #pragma unroll
    for (int i = 0; i < 16; i += 2) {   // rows y, y+1
      const int y = y0 + yb + i;
      // prefetch rows y+11, y+12 (consumed 2 pairs later); vmcnt only,
      // unaffected by the lgkmcnt fences.
      pipe[(i + 4) & 7] = row_load(s, y + 11, col, lane);
      pipe[(i + 5) & 7] = row_load(s, y + 12, col, lane);

      const int ls0 = (i + 7) & 15;
      const int ls1 = (i + 8) & 15;

      RowLd t0 = pipe[i & 7];
      RowLd t1 = pipe[(i + 1) & 7];
      float* st0 = smem[wid][0];
      float* st1 = smem[wid][1];
      LDS_FENCE();                    // WAR: previous iteration's reads done
      stage_row(st0, t0, lane);
      stage_row(st1, t1, lane);
      LDS_FENCE();                    // RAW: writes visible before reads
      float lh1, rh1;
      tree_sums(st0, lane, t0.wc, rlh[ls0], rrh[ls0]);  // commit row y+7
      rw[ls0] = t0.wc;
      tree_sums(st1, lane, t1.wc, lh1, rh1);            // row y+8 in temps
      const float w1 = t1.wc;                           // (slot ls1 still live)

      // ---- row y: slide windows y-1 -> y (reads OLD slot ls1 = row y-8)
      ua += rlh[i];   ua -= rlh[ls1];
      ub += rrh[i];   ub -= rrh[ls1];
      uc += rw [i];   uc -= rw [ls1];
      da += rlh[ls0]; da -= rlh[(i + 15) & 15];
      db += rrh[ls0]; db -= rrh[(i + 15) & 15];
      dc += rw [ls0]; dc -= rw [(i + 15) & 15];
      const float o0 = out_px(ua, ub, uc, da, db, dc, rlh[i], rrh[i], rw[i]);

      // commit row y+8 (row y-8 now dead)
      rlh[ls1] = lh1; rrh[ls1] = rh1; rw[ls1] = w1;

      // ---- row y+1: slide windows y -> y+1
      const int i1 = i + 1;
      ua += rlh[i1];  ua -= rlh[(i1 + 8) & 15];
      ub += rrh[i1];  ub -= rrh[(i1 + 8) & 15];
      uc += rw [i1];  uc -= rw [(i1 + 8) & 15];
      da += rlh[ls1]; da -= rlh[i];
      db += rrh[ls1]; db -= rrh[i];
      dc += rw [ls1]; dc -= rw [i];
      const float o1 = out_px(ua, ub, uc, da, db, dc, rlh[i1], rrh[i1], rw[i1]);

      d[(size_t)y * WW + col]       = o0;
      d[(size_t)(y + 1) * WW + col] = o1;
    }
  }
}

extern "C" void kernel_launch(void* const* d_in, const int* in_sizes, int n_in,
                              void* d_out, int out_size, void* d_ws, size_t ws_size,
                              hipStream_t stream) {
  const float* in = (const float*)d_in[0];
  float* out = (float*)d_out;
  float* ws  = (float*)d_ws;   // 12*1024*1024*4 = 50.3 MB scratch

  dim3 grid(WW / 64, 8, NIMG);
  dim3 block(256);

  swf_step<<<grid, block, 0, stream>>>(in, out);
  swf_step<<<grid, block, 0, stream>>>(out, ws);
  swf_step<<<grid, block, 0, stream>>>(ws, out);
}

// Round 15
// 123.030 us; speedup vs baseline: 3.1988x; 3.1988x over previous
//
#include <hip/hip_runtime.h>

#define HH 1024
#define WW 1024
#define NIMG 12
#define OUTC 50            // output cols per wave (lanes 7..56)
#define NSTRIP 21          // ceil(1024/50)

// fwd8: F(l) = sum of values at lanes l..l+7 (valid for lane <= 56), balanced
// pairwise tree — identical grouping to all previous rounds (bitwise-stable).
__device__ __forceinline__ float fwd8(float a) {
  a += __shfl_down(a, 1, 64);
  a += __shfl_down(a, 2, 64);
  a += __shfl_down(a, 4, 64);
  return a;
}

// Zero-padded pixel load.
__device__ __forceinline__ float load_px(const float* __restrict__ s, int ry, int cl) {
  if ((unsigned)ry < (unsigned)HH && (unsigned)cl < (unsigned)WW)
    return s[(size_t)ry * WW + cl];
  return 0.0f;
}

// first-wins argmin combine: keep a unless |b| strictly smaller (tie -> a).
__device__ __forceinline__ float winner(float a, float b) {
  return (fabsf(b) < fabsf(a)) ? b : a;
}

__device__ __forceinline__ float out_px(float ua, float ub, float uc,
                                        float da, float db, float dc,
                                        float lh0, float rh0, float w0) {
  const float ih = 1.0f / 120.0f, iq = 1.0f / 64.0f;
  const float nw0 = -w0;
  const float Ls = ua + da - lh0;
  const float Rs = ub + db - rh0;
  const float Us = ua + ub - uc;
  const float Ds = da + db - dc;
  float d0 = fmaf(Ls, ih, nw0);
  float d1 = fmaf(Rs, ih, nw0);
  float d2 = fmaf(Us, ih, nw0);
  float d3 = fmaf(Ds, ih, nw0);
  float d4 = fmaf(ua, iq, nw0);
  float d5 = fmaf(ub, iq, nw0);
  float d6 = fmaf(da, iq, nw0);
  float d7 = fmaf(db, iq, nw0);
  float w01 = winner(d0, d1), w23 = winner(d2, d3);
  float w45 = winner(d4, d5), w67 = winner(d6, d7);
  float bd = winner(winner(w01, w23), winner(w45, w67));
  return w0 + bd;
}

// One SWF step, halo-lane tiling: wave loads x[c0-7 .. c0+56] (lane L loads
// x[c0-7+L], ONE load/row) and outputs cols c0..c0+49 (lanes 7..56).
// f = fwd8(wc):  rh(col) = f@L,  lh(col) = shfl_up(f,7) = f@(L-7).
// Per row: 1 load + 4 DS ops (one 3-deep chain + 1), no selects, no LDS.
// 16-deep (lh,rh,w) register ring; sliding vertical windows; 2 rows/iter;
// 8-slot single-float load pipe, 6 rows ahead.
__global__ __launch_bounds__(256, 4) void swf_step(const float* __restrict__ src,
                                                   float* __restrict__ dst) {
  const int lane = threadIdx.x & 63;
  const int wid  = threadIdx.x >> 6;
  const int cl   = blockIdx.x * OUTC - 7 + lane;       // load col
  const int y0   = (blockIdx.y * 4 + wid) * 32;        // 32 chunks x 32 rows
  const float* s = src + (size_t)blockIdx.z * HH * WW;
  float* d       = dst + (size_t)blockIdx.z * HH * WW;

  const int  colOut  = cl;                             // c0 + (lane-7)
  const bool writeOK = (lane >= 7) && (lane <= 56) && (colOut < WW);

  float rlh[16], rrh[16], rw[16];

  // Prologue: rows y0-8 .. y0+6 into slot row&15 = (j+8)&15.
  #pragma unroll
  for (int j = 0; j < 15; ++j) {
    const int slot = (j + 8) & 15;
    float wc = load_px(s, y0 - 8 + j, cl);
    float f  = fwd8(wc);
    rlh[slot] = __shfl_up(f, 7, 64);
    rrh[slot] = f;
    rw [slot] = wc;
  }

  // Sliding accumulators for "previous output row" y0-1:
  //   u* over rows y0-8..y0-1 (slots 8..15), d* over rows y0-1..y0+6 (15,0..6)
  float ua = 0.f, ub = 0.f, uc = 0.f, da = 0.f, db = 0.f, dc = 0.f;
  #pragma unroll
  for (int j = 0; j < 8; ++j) {
    const int sl = (8 + j) & 15;
    ua += rlh[sl]; ub += rrh[sl]; uc += rw[sl];
  }
  #pragma unroll
  for (int j = 0; j < 8; ++j) {
    const int sl = (15 + j) & 15;
    da += rlh[sl]; db += rrh[sl]; dc += rw[sl];
  }

  // Load pipe: slot(row) = (row - y0 - 7) & 7. Prime rows y0+7 .. y0+12.
  float pipe[8];
  #pragma unroll
  for (int k = 0; k < 6; ++k) pipe[k] = load_px(s, y0 + 7 + k, cl);

  #pragma unroll 1
  for (int yb = 0; yb < 32; yb += 16) {
    #pragma unroll
    for (int i = 0; i < 16; i += 2) {   // rows y, y+1
      const int y = y0 + yb + i;
      // prefetch rows y+13, y+14 (consumed 3 pair-iters later);
      // live slots at this point are i..i+5, writing (i+6)&7, (i+7)&7.
      pipe[(i + 6) & 7] = load_px(s, y + 13, cl);
      pipe[(i + 7) & 7] = load_px(s, y + 14, cl);

      const int ls0 = (i + 7) & 15;
      const int ls1 = (i + 8) & 15;

      // rows y+7, y+8: two independent fwd8 chains
      const float t0 = pipe[i & 7];
      const float t1 = pipe[(i + 1) & 7];
      float f0 = fwd8(t0);
      float f1 = fwd8(t1);
      float l0 = __shfl_up(f0, 7, 64);
      float l1 = __shfl_up(f1, 7, 64);

      // commit row y+7 (slot ls0 held dead row y-9)
      rlh[ls0] = l0; rrh[ls0] = f0; rw[ls0] = t0;
      // row y+8 stays in temps (l1,f1,t1): slot ls1 still live (row y-8)

      // ---- row y: slide windows y-1 -> y (reads OLD slot ls1 = row y-8)
      ua += rlh[i];   ua -= rlh[ls1];
      ub += rrh[i];   ub -= rrh[ls1];
      uc += rw [i];   uc -= rw [ls1];
      da += rlh[ls0]; da -= rlh[(i + 15) & 15];
      db += rrh[ls0]; db -= rrh[(i + 15) & 15];
      dc += rw [ls0]; dc -= rw [(i + 15) & 15];
      const float o0 = out_px(ua, ub, uc, da, db, dc, rlh[i], rrh[i], rw[i]);

      // commit row y+8 (row y-8 now dead)
      rlh[ls1] = l1; rrh[ls1] = f1; rw[ls1] = t1;

      // ---- row y+1: slide windows y -> y+1
      const int i1 = i + 1;
      ua += rlh[i1];  ua -= rlh[(i1 + 8) & 15];
      ub += rrh[i1];  ub -= rrh[(i1 + 8) & 15];
      uc += rw [i1];  uc -= rw [(i1 + 8) & 15];
      da += rlh[ls1]; da -= rlh[i];
      db += rrh[ls1]; db -= rrh[i];
      dc += rw [ls1]; dc -= rw [i];
      const float o1 = out_px(ua, ub, uc, da, db, dc, rlh[i1], rrh[i1], rw[i1]);

      if (writeOK) {
        d[(size_t)y * WW + colOut]       = o0;
        d[(size_t)(y + 1) * WW + colOut] = o1;
      }
    }
  }
}

extern "C" void kernel_launch(void* const* d_in, const int* in_sizes, int n_in,
                              void* d_out, int out_size, void* d_ws, size_t ws_size,
                              hipStream_t stream) {
  const float* in = (const float*)d_in[0];
  float* out = (float*)d_out;
  float* ws  = (float*)d_ws;   // 12*1024*1024*4 = 50.3 MB scratch

  dim3 grid(NSTRIP, 8, NIMG);  // 21 col-strips x 50 cols, 8 y-groups x4 waves, 12 planes
  dim3 block(256);

  swf_step<<<grid, block, 0, stream>>>(in, out);
  swf_step<<<grid, block, 0, stream>>>(out, ws);
  swf_step<<<grid, block, 0, stream>>>(ws, out);
}